// Round 9
// baseline (124.732 us; speedup 1.0000x reference)
//
#include <hip/hip_runtime.h>

#define NN 8
#define HH 512
#define WW 512
#define CC 3
#define KK 5
#define PADP 2
#define WROWF (WW * CC)             // 1536 floats per image row
#define NBLOCKS 16384               // 128-thread blocks = 2 independent waves,
                                    // each wave owns one 64-px row-tile (32768 tiles)

typedef float f4a __attribute__((ext_vector_type(4), aligned(4)));

struct Row { f4a L0, L1, L2, L3; };     // 15-float window f0..f14 (L3 overlaps at f11)

__device__ __forceinline__ void load_row(const float* rb, Row& r) {
    r.L0 = *(const f4a*)(rb);
    r.L1 = *(const f4a*)(rb + 4);
    r.L2 = *(const f4a*)(rb + 8);
    r.L3 = *(const f4a*)(rb + 11);
}

// taps: dw uses floats [3*dw .. 3*dw+2] of the window
__device__ __forceinline__ void fma_row(const Row& r, const float* wp,
                                        float& a0, float& a1, float& a2) {
    const float w0 = wp[0], w1 = wp[1], w2 = wp[2], w3 = wp[3], w4 = wp[4];
    a0 = fmaf(r.L0[0], w0, a0); a1 = fmaf(r.L0[1], w0, a1); a2 = fmaf(r.L0[2], w0, a2);
    a0 = fmaf(r.L0[3], w1, a0); a1 = fmaf(r.L1[0], w1, a1); a2 = fmaf(r.L1[1], w1, a2);
    a0 = fmaf(r.L1[2], w2, a0); a1 = fmaf(r.L1[3], w2, a1); a2 = fmaf(r.L2[0], w2, a2);
    a0 = fmaf(r.L2[1], w3, a0); a1 = fmaf(r.L2[2], w3, a1); a2 = fmaf(r.L2[3], w3, a2);
    a0 = fmaf(r.L3[1], w4, a0); a1 = fmaf(r.L3[2], w4, a1); a2 = fmaf(r.L3[3], w4, a2);
}

#define GLDS16(gp, lp) __builtin_amdgcn_global_load_lds( \
    (const __attribute__((address_space(1))) void*)(gp), \
    (__attribute__((address_space(3))) void*)(lp), 16, 0, 0)
#define GLDS4(gp, lp) __builtin_amdgcn_global_load_lds( \
    (const __attribute__((address_space(1))) void*)(gp), \
    (__attribute__((address_space(3))) void*)(lp), 4, 0, 0)

__global__ __launch_bounds__(128, 6) void conv_local_kernel(
    const float* __restrict__ in,   // (N,H,W,C)
    const float* __restrict__ wt,   // (N,H,W,25)
    float* __restrict__ out)        // (N,H,W,C)
{
    // Two fully independent waves per block: own LDS slice, own weight stream,
    // no __syncthreads anywhere. 12.8 KB/block -> 12 blocks/CU = 24 waves/CU.
    __shared__ float w_lds[2][64 * KK * KK];   // 2 x 6.4 KB

    const int lane = threadIdx.x & 63;
    const int wv   = threadIdx.x >> 6;
    // bijective XCD swizzle: 16384 blocks = 8 x 2048; per-XCD tiles are a
    // contiguous range (each XCD streams exactly one image's weights linearly)
    const int bs = ((blockIdx.x & 7) << 11) | (blockIdx.x >> 3);
    const int t  = (bs << 1) | wv;           // row-tile id, 0..32767
    const int w0 = (t & 7) << 6;             // 0..448 (wave-uniform)
    const int h  = (t >> 3) & (HH - 1);      // wave-uniform
    const int n  = t >> 12;

    const long pix0 = ((long)(n * HH + h)) * WW + w0;
    const float* inb = in + (size_t)n * (HH * WW * CC);

    // ---- stage this wave's 64x25 weights: async global->LDS, coalesced ----
    {
        const char* s0 = (const char*)(wt + pix0 * (KK * KK));
        float* wl = w_lds[wv];
#pragma unroll
        for (int it = 0; it < 6; ++it)
            GLDS16(s0 + it * 1024 + lane * 16, wl + it * 256);
        GLDS4(s0 + 6144 + lane * 4, wl + 1536);
    }

    const float* wp = &w_lds[wv][lane * (KK * KK)];
    const bool fast = (w0 != 0) && (w0 != WW - 64) && (h >= PADP) && (h < HH - PADP);

    if (fast) {
        // 5 input rows gh = h-2 .. h+2, A/B register rotation (R7-proven)
        const float* rb = inb + ((long)(h - PADP) * WW + (w0 + lane - PADP)) * CC;
        Row A, B;
        load_row(rb, A);
        load_row(rb + 1 * WROWF, B);
        // drain global_load_lds before ds_reads (dependency not register-tracked)
        asm volatile("s_waitcnt vmcnt(0)" ::: "memory");
        __builtin_amdgcn_sched_barrier(0);

        float a0 = 0.f, a1 = 0.f, a2 = 0.f;
        fma_row(A, wp + 0,  a0, a1, a2);
        load_row(rb + 2 * WROWF, A);
        fma_row(B, wp + 5,  a0, a1, a2);
        load_row(rb + 3 * WROWF, B);
        fma_row(A, wp + 10, a0, a1, a2);
        load_row(rb + 4 * WROWF, A);
        fma_row(B, wp + 15, a0, a1, a2);
        fma_row(A, wp + 20, a0, a1, a2);

        float* o = out + (pix0 + lane) * CC;
        o[0] = a0; o[1] = a1; o[2] = a2;
    } else {
        asm volatile("s_waitcnt vmcnt(0)" ::: "memory");
        __builtin_amdgcn_sched_barrier(0);
        // border row-tiles: predicated scalar path (R1-proven), weights from LDS
        const int w = w0 + lane;
        float a0 = 0.f, a1 = 0.f, a2 = 0.f;
#pragma unroll
        for (int dh = 0; dh < KK; ++dh) {
            const int ih = h + dh - PADP;
            const bool rok = ((unsigned)ih < (unsigned)HH);
#pragma unroll
            for (int dw = 0; dw < KK; ++dw) {
                const int iw = w + dw - PADP;
                const bool ok = rok && ((unsigned)iw < (unsigned)WW);
                const float* p = inb + ((long)(ih * WW + iw)) * CC;
                float v0 = ok ? p[0] : 0.f;
                float v1 = ok ? p[1] : 0.f;
                float v2 = ok ? p[2] : 0.f;
                const float wv_ = wp[dh * KK + dw];
                a0 = fmaf(v0, wv_, a0);
                a1 = fmaf(v1, wv_, a1);
                a2 = fmaf(v2, wv_, a2);
            }
        }
        float* o = out + (pix0 + lane) * CC;
        o[0] = a0; o[1] = a1; o[2] = a2;
    }
}

extern "C" void kernel_launch(void* const* d_in, const int* in_sizes, int n_in,
                              void* d_out, int out_size, void* d_ws, size_t ws_size,
                              hipStream_t stream) {
    const float* in = (const float*)d_in[0];   // (8,512,512,3) f32
    const float* wt = (const float*)d_in[1];   // (8,512,512,25) f32
    float* out = (float*)d_out;                // (8,512,512,3) f32

    conv_local_kernel<<<NBLOCKS, 128, 0, stream>>>(in, wt, out);
}

// Round 10
// 64.478 us; speedup vs baseline: 1.9345x; 1.9345x over previous
//
#include <hip/hip_runtime.h>

#define NN 8
#define HH 512
#define WW 512
#define CC 3
#define KK 5
#define PADP 2
#define WROWF (WW * CC)          // 1536 floats per image row
#define NT 4                     // row-tiles per block (rows h0..h0+3, one 64-px wseg)
#define NBLOCKS (NN * HH * WW / 64 / NT)   // 8192

typedef float f4a __attribute__((ext_vector_type(4), aligned(4)));

struct Row { f4a L0, L1, L2, L3; };   // 15-float window f0..f14 (L3 overlaps at f11)

__device__ __forceinline__ void load_row(const float* rb, Row& r) {
    r.L0 = *(const f4a*)(rb);
    r.L1 = *(const f4a*)(rb + 4);
    r.L2 = *(const f4a*)(rb + 8);
    r.L3 = *(const f4a*)(rb + 11);
}

__device__ __forceinline__ void fma_row(const Row& r, const float* wp,
                                        float& a0, float& a1, float& a2) {
    const float w0 = wp[0], w1 = wp[1], w2 = wp[2], w3 = wp[3], w4 = wp[4];
    a0 = fmaf(r.L0[0], w0, a0); a1 = fmaf(r.L0[1], w0, a1); a2 = fmaf(r.L0[2], w0, a2);
    a0 = fmaf(r.L0[3], w1, a0); a1 = fmaf(r.L1[0], w1, a1); a2 = fmaf(r.L1[1], w1, a2);
    a0 = fmaf(r.L1[2], w2, a0); a1 = fmaf(r.L1[3], w2, a1); a2 = fmaf(r.L2[0], w2, a2);
    a0 = fmaf(r.L2[1], w3, a0); a1 = fmaf(r.L2[2], w3, a1); a2 = fmaf(r.L2[3], w3, a2);
    a0 = fmaf(r.L3[1], w4, a0); a1 = fmaf(r.L3[2], w4, a1); a2 = fmaf(r.L3[3], w4, a2);
}

#define GLDS16(gp, lp) __builtin_amdgcn_global_load_lds( \
    (const __attribute__((address_space(1))) void*)(gp), \
    (__attribute__((address_space(3))) void*)(lp), 16, 0, 0)
#define GLDS4(gp, lp) __builtin_amdgcn_global_load_lds( \
    (const __attribute__((address_space(1))) void*)(gp), \
    (__attribute__((address_space(3))) void*)(lp), 4, 0, 0)

// stage one tile's 64x25 weights (6400B) into an LDS buffer: 7 async ops
#define STAGE(dst, row) do {                                            \
    const char* _s = (const char*)(wt + ((long)(nHH + (row)) * WW + w0) * (KK * KK)); \
    _Pragma("unroll")                                                   \
    for (int _it = 0; _it < 6; ++_it)                                   \
        GLDS16(_s + _it * 1024 + lane * 16, (dst) + _it * 256);         \
    GLDS4(_s + 6144 + lane * 4, (dst) + 1536);                          \
} while (0)

// counted wait: all OLDER vmem ops done, newest N stay in flight
#define WAITK(N) do {                                                   \
    asm volatile("s_waitcnt vmcnt(" #N ")" ::: "memory");               \
    __builtin_amdgcn_sched_barrier(0);                                  \
} while (0)

// interior tile: 5 register rows x 5 weight rows, store 1 output row
#define CTILE(Ra, Rb, Rc, Rd, Re, WBUF, row) do {                       \
    const float* _wp = &WBUF[lane * (KK * KK)];                         \
    float a0 = 0.f, a1 = 0.f, a2 = 0.f;                                 \
    fma_row(Ra, _wp + 0,  a0, a1, a2);                                  \
    fma_row(Rb, _wp + 5,  a0, a1, a2);                                  \
    fma_row(Rc, _wp + 10, a0, a1, a2);                                  \
    fma_row(Rd, _wp + 15, a0, a1, a2);                                  \
    fma_row(Re, _wp + 20, a0, a1, a2);                                  \
    float* _o = out + ((long)(nHH + (row)) * WW + w0 + lane) * CC;      \
    _o[0] = a0; _o[1] = a1; _o[2] = a2;                                 \
} while (0)

// border tile: predicated scalar path, weights from LDS
#define STILE(WBUF, row) do {                                           \
    const float* _wp = &WBUF[lane * (KK * KK)];                         \
    const int _w = w0 + lane;                                           \
    float a0 = 0.f, a1 = 0.f, a2 = 0.f;                                 \
    _Pragma("unroll")                                                   \
    for (int dh = 0; dh < KK; ++dh) {                                   \
        const int ih = (row) + dh - PADP;                               \
        const bool rok = ((unsigned)ih < (unsigned)HH);                 \
        _Pragma("unroll")                                               \
        for (int dw = 0; dw < KK; ++dw) {                               \
            const int iw = _w + dw - PADP;                              \
            const bool ok = rok && ((unsigned)iw < (unsigned)WW);       \
            const float* p = inb + ((long)(ih * WW + iw)) * CC;         \
            float v0 = ok ? p[0] : 0.f;                                 \
            float v1 = ok ? p[1] : 0.f;                                 \
            float v2 = ok ? p[2] : 0.f;                                 \
            const float wv = _wp[dh * KK + dw];                         \
            a0 = fmaf(v0, wv, a0);                                      \
            a1 = fmaf(v1, wv, a1);                                      \
            a2 = fmaf(v2, wv, a2);                                      \
        }                                                               \
    }                                                                   \
    float* _o = out + ((long)(nHH + (row)) * WW + w0 + lane) * CC;      \
    _o[0] = a0; _o[1] = a1; _o[2] = a2;                                 \
} while (0)

__global__ __launch_bounds__(64, 3) void conv_local_kernel(
    const float* __restrict__ in,   // (N,H,W,C)
    const float* __restrict__ wt,   // (N,H,W,25)
    float* __restrict__ out)        // (N,H,W,C)
{
    __shared__ float bufA[64 * KK * KK];   // 6.4 KB
    __shared__ float bufB[64 * KK * KK];   // 6.4 KB  -> 12.8 KB total, 12 blocks/CU

    const int lane = threadIdx.x;
    // bijective XCD swizzle: 8192 blocks = 8 x 1024; per-XCD range contiguous
    const int b    = ((blockIdx.x & 7) << 10) | (blockIdx.x >> 3);
    const int wseg = b & 7;
    const int hg   = (b >> 3) & 127;
    const int n    = b >> 10;
    const int w0   = wseg << 6;       // 0..448
    const int h0   = hg << 2;         // 0..508
    const int nHH  = n * HH;

    const float* inb = in + (size_t)n * (HH * WW * CC);

    // prologue: stage tile0 weights immediately (HBM stream starts now)
    STAGE(bufA, h0 + 0);

    const bool interior = (wseg >= 1) && (wseg <= 6) && (hg >= 1) && (hg <= 126);

    if (interior) {
        // upfront input rows h0-2 .. h0+2 (tile0's window)
        const float* rb = inb + ((long)(h0 - PADP) * WW + (w0 + lane - PADP)) * CC;
        Row R0, R1, R2, R3, R4, R5, R6, R7;
        load_row(rb + 0 * WROWF, R0);
        load_row(rb + 1 * WROWF, R1);
        load_row(rb + 2 * WROWF, R2);
        load_row(rb + 3 * WROWF, R3);
        load_row(rb + 4 * WROWF, R4);
        STAGE(bufB, h0 + 1);             // tile1 weights in flight
        // ---- tile0 ----
        load_row(rb + 5 * WROWF, R5);    // roll row h0+3
        WAITK(11);                       // drain tile0 wt + upfront rows; keep {bufB(7), R5(4)}
        CTILE(R0, R1, R2, R3, R4, bufA, h0 + 0);
        // ---- tile1 ----
        STAGE(bufA, h0 + 2);             // tile2 weights in flight
        load_row(rb + 6 * WROWF, R6);    // roll row h0+4
        WAITK(11);                       // drain bufB stage + R5 + stores; keep {bufA(7), R6(4)}
        CTILE(R1, R2, R3, R4, R5, bufB, h0 + 1);
        // ---- tile2 ----
        STAGE(bufB, h0 + 3);             // tile3 weights in flight
        load_row(rb + 7 * WROWF, R7);    // roll row h0+5
        WAITK(11);                       // keep {bufB(7), R7(4)}
        CTILE(R2, R3, R4, R5, R6, bufA, h0 + 2);
        // ---- tile3 ----
        WAITK(0);
        CTILE(R3, R4, R5, R6, R7, bufB, h0 + 3);
    } else {
        // border blocks: same double-buffered weight pipeline, scalar compute
        STAGE(bufB, h0 + 1);
        WAITK(7);                        // drain tile0 wt; keep bufB stage
        STILE(bufA, h0 + 0);
        STAGE(bufA, h0 + 2);
        WAITK(7);
        STILE(bufB, h0 + 1);
        STAGE(bufB, h0 + 3);
        WAITK(7);
        STILE(bufA, h0 + 2);
        WAITK(0);
        STILE(bufB, h0 + 3);
    }
}

extern "C" void kernel_launch(void* const* d_in, const int* in_sizes, int n_in,
                              void* d_out, int out_size, void* d_ws, size_t ws_size,
                              hipStream_t stream) {
    const float* in = (const float*)d_in[0];   // (8,512,512,3) f32
    const float* wt = (const float*)d_in[1];   // (8,512,512,25) f32
    float* out = (float*)d_out;                // (8,512,512,3) f32

    conv_local_kernel<<<NBLOCKS, 64, 0, stream>>>(in, wt, out);
}